// Round 8
// baseline (569.910 us; speedup 1.0000x reference)
//
#include <hip/hip_runtime.h>
#include <hip/hip_bf16.h>

// Problem constants
#define TN 2000
#define UN 50000
#define TF 16
#define NCOL 48      // padded N: 36 emb cols + ones col (36) + 11 zero cols
#define UNP 50016    // padded K: 1563 steps * 32
#define KSTEPS 1563  // ceil(50000/32); step 1562 is the partial tail
#define KFULL 1562   // steps with all 32 k valid (50000 = 1562*32 + 16)
#define KCHUNKS 63   // finer K-split: 16x63=1008 blocks ~ 3.9/CU (R7: was 48, 3/CU)
#define SPC 25       // ceil(1563/63); 63*25=1575, last chunk 1550..1563 non-empty
#define MTILES 125   // 2000/16

typedef __attribute__((ext_vector_type(8))) short short8;
typedef __attribute__((ext_vector_type(4))) float f32x4;
typedef __attribute__((ext_vector_type(4))) int i32x4;

__device__ inline unsigned short f2bf(float f) {
    unsigned int x = __float_as_uint(f);
    x += 0x7FFFu + ((x >> 16) & 1u);      // round-to-nearest-even
    return (unsigned short)(x >> 16);
}

// Kernel 1: gather per-user embeddings into bf16 in MFMA B-FRAGMENT ORDER:
//   BS[((ks*3 + tile)*64 + lane)*8 + j] = B[k=ks*32+(lane>>4)*8+j][n=tile*16+(lane&15)]
// so the gemm's three B-loads per step are fully coalesced 1KB wave reads.
__global__ void build_uembT(const int* __restrict__ U,
                            const float* __restrict__ e0, const float* __restrict__ e1,
                            const float* __restrict__ e2, const float* __restrict__ e3,
                            const float* __restrict__ e4, const float* __restrict__ e5,
                            unsigned short* __restrict__ BS) {
    int u = blockIdx.x * 256 + threadIdx.x;   // k index
    int c = blockIdx.y;                        // n index 0..47, wave-uniform
    if (u >= UNP) return;
    unsigned short val = 0;
    if (u < UN) {
        if (c < 36) {
            int f = c / 6, h = c - f * 6;      // uniform scalar math
            const float* t = (f == 0) ? e0 : (f == 1) ? e1 : (f == 2) ? e2
                           : (f == 3) ? e3 : (f == 4) ? e4 : e5;
            int idx = U[u * 6 + f];
            val = f2bf(t[idx * 6 + h]);
        } else if (c == 36) {
            val = 0x3F80;                      // ones column -> counts
        }
    }
    int ks   = u >> 5;
    int g    = (u & 31) >> 3;
    int j    = u & 7;
    int lane = g * 16 + (c & 15);
    int tile = c >> 4;
    BS[(((size_t)ks * 3 + tile) * 64 + lane) * 8 + j] = val;
}

// mask values are exactly 0/1, so bf16 packed pair = lo*0x3F80 + hi*0x3F800000
__device__ inline short8 mask_to_bf16(i32x4 v0, i32x4 v1) {
    union { short8 s; unsigned int i[4]; } a;
    a.i[0] = (unsigned)v0.x * 0x3F80u + (unsigned)v0.y * 0x3F800000u;
    a.i[1] = (unsigned)v0.z * 0x3F80u + (unsigned)v0.w * 0x3F800000u;
    a.i[2] = (unsigned)v1.x * 0x3F80u + (unsigned)v1.y * 0x3F800000u;
    a.i[3] = (unsigned)v1.z * 0x3F80u + (unsigned)v1.w * 0x3F800000u;
    return a.s;
}

// Kernel 2: bf16 MFMA GEMM, 2 M-tiles per wave (B fragments reused):
//   partial[m][ky][n] = sum_{k in chunk ky} mask(m,k) * Uemb[k][n]
// grid (16,KCHUNKS): slot s = blockIdx.x*4+wave handles mtile s and s+64.
__global__ __launch_bounds__(256) void masked_gemm(
        const int* __restrict__ mask, const unsigned short* __restrict__ BS,
        float* __restrict__ partial) {
    int wave = threadIdx.x >> 6;
    int lane = threadIdx.x & 63;
    int slot = blockIdx.x * 4 + wave;     // 0..63
    int mt0 = slot;                        // always < 125
    int mt1 = slot + 64;
    bool two = (mt1 < MTILES);
    int r  = lane & 15;
    int g8 = (lane >> 4) * 8;
    int ky = blockIdx.y;

    int ks0 = ky * SPC;
    int ks1 = ks0 + SPC; if (ks1 > KSTEPS) ks1 = KSTEPS;
    int ksf = (ks1 < KFULL) ? ks1 : KFULL;   // full (unguarded) steps

    f32x4 acc00 = {0,0,0,0}, acc01 = {0,0,0,0}, acc02 = {0,0,0,0};
    f32x4 acc10 = {0,0,0,0}, acc11 = {0,0,0,0}, acc12 = {0,0,0,0};

    const int* arow0 = mask + (size_t)(mt0 * 16 + r) * UN + g8;
    const int* arow1 = arow0 + (size_t)64 * 16 * UN;   // mt1 = mt0+64
    const short8* bs = (const short8*)BS + lane;       // fragment-order B

    if (two) {
        #pragma unroll 3
        for (int ks = ks0; ks < ksf; ++ks) {
            int gk = ks * 32;
            const i32x4* p0 = (const i32x4*)(arow0 + gk);
            const i32x4* p1 = (const i32x4*)(arow1 + gk);
            i32x4 u0 = p0[0], u1 = p0[1];
            i32x4 w0 = p1[0], w1 = p1[1];
            short8 a0 = mask_to_bf16(u0, u1);
            short8 a1 = mask_to_bf16(w0, w1);
            short8 f0 = bs[(size_t)(ks * 3    ) * 64];
            short8 f1 = bs[(size_t)(ks * 3 + 1) * 64];
            short8 f2 = bs[(size_t)(ks * 3 + 2) * 64];
            acc00 = __builtin_amdgcn_mfma_f32_16x16x32_bf16(a0, f0, acc00, 0, 0, 0);
            acc01 = __builtin_amdgcn_mfma_f32_16x16x32_bf16(a0, f1, acc01, 0, 0, 0);
            acc02 = __builtin_amdgcn_mfma_f32_16x16x32_bf16(a0, f2, acc02, 0, 0, 0);
            acc10 = __builtin_amdgcn_mfma_f32_16x16x32_bf16(a1, f0, acc10, 0, 0, 0);
            acc11 = __builtin_amdgcn_mfma_f32_16x16x32_bf16(a1, f1, acc11, 0, 0, 0);
            acc12 = __builtin_amdgcn_mfma_f32_16x16x32_bf16(a1, f2, acc12, 0, 0, 0);
        }
    } else {
        #pragma unroll 3
        for (int ks = ks0; ks < ksf; ++ks) {
            int gk = ks * 32;
            const i32x4* p0 = (const i32x4*)(arow0 + gk);
            i32x4 u0 = p0[0], u1 = p0[1];
            short8 a0 = mask_to_bf16(u0, u1);
            short8 f0 = bs[(size_t)(ks * 3    ) * 64];
            short8 f1 = bs[(size_t)(ks * 3 + 1) * 64];
            short8 f2 = bs[(size_t)(ks * 3 + 2) * 64];
            acc00 = __builtin_amdgcn_mfma_f32_16x16x32_bf16(a0, f0, acc00, 0, 0, 0);
            acc01 = __builtin_amdgcn_mfma_f32_16x16x32_bf16(a0, f1, acc01, 0, 0, 0);
            acc02 = __builtin_amdgcn_mfma_f32_16x16x32_bf16(a0, f2, acc02, 0, 0, 0);
        }
    }
    if (ks0 <= KFULL && ks1 > KFULL) {    // tail step (only chunk 62): k 49984..50015
        int tk = KFULL * 32;
        short8 a0 = {0,0,0,0,0,0,0,0}, a1 = {0,0,0,0,0,0,0,0};
        if (g8 < 16) {                    // k-groups at 49984, 49992 are fully valid
            const i32x4* p0 = (const i32x4*)(arow0 + tk);
            a0 = mask_to_bf16(p0[0], p0[1]);
            if (two) {
                const i32x4* p1 = (const i32x4*)(arow1 + tk);
                a1 = mask_to_bf16(p1[0], p1[1]);
            }
        }
        short8 t0 = bs[(size_t)(KFULL * 3    ) * 64];
        short8 t1 = bs[(size_t)(KFULL * 3 + 1) * 64];
        short8 t2 = bs[(size_t)(KFULL * 3 + 2) * 64];
        acc00 = __builtin_amdgcn_mfma_f32_16x16x32_bf16(a0, t0, acc00, 0, 0, 0);
        acc01 = __builtin_amdgcn_mfma_f32_16x16x32_bf16(a0, t1, acc01, 0, 0, 0);
        acc02 = __builtin_amdgcn_mfma_f32_16x16x32_bf16(a0, t2, acc02, 0, 0, 0);
        if (two) {
            acc10 = __builtin_amdgcn_mfma_f32_16x16x32_bf16(a1, t0, acc10, 0, 0, 0);
            acc11 = __builtin_amdgcn_mfma_f32_16x16x32_bf16(a1, t1, acc11, 0, 0, 0);
            acc12 = __builtin_amdgcn_mfma_f32_16x16x32_bf16(a1, t2, acc12, 0, 0, 0);
        }
    }

    // C/D layout: col = lane&15, row = (lane>>4)*4 + reg   [HW-verified]
    int rbase = (lane >> 4) * 4;
    int col   = lane & 15;
    #pragma unroll
    for (int reg = 0; reg < 4; ++reg) {
        size_t rb = ((size_t)(mt0 * 16 + rbase + reg) * KCHUNKS + ky) * NCOL;
        partial[rb + col]      = acc00[reg];
        partial[rb + col + 16] = acc01[reg];
        if (col < 5) partial[rb + col + 32] = acc02[reg];
    }
    if (two) {
        #pragma unroll
        for (int reg = 0; reg < 4; ++reg) {
            size_t rb = ((size_t)(mt1 * 16 + rbase + reg) * KCHUNKS + ky) * NCOL;
            partial[rb + col]      = acc10[reg];
            partial[rb + col + 16] = acc11[reg];
            if (col < 5) partial[rb + col + 32] = acc12[reg];
        }
    }
}

// Kernel 3: out[t] = concat(T_static[t], sum_ky partial[t][ky][0:36] / sum_ky partial[t][ky][36])
__global__ void finalize(const float* __restrict__ T_static,
                         const float* __restrict__ partial,
                         float* __restrict__ out) {
    int t = blockIdx.x;
    int c = threadIdx.x;
    if (c >= TF + 36) return;
    float v;
    if (c < TF) {
        v = T_static[(size_t)t * TF + c];
    } else {
        int n = c - TF;
        const float* base = partial + (size_t)t * KCHUNKS * NCOL;
        float s = 0.f, cnt = 0.f;
        #pragma unroll 7
        for (int ky = 0; ky < KCHUNKS; ++ky) {
            s   += base[ky * NCOL + n];
            cnt += base[ky * NCOL + 36];
        }
        v = s / cnt;
    }
    out[(size_t)t * (TF + 36) + c] = v;
}

extern "C" void kernel_launch(void* const* d_in, const int* in_sizes, int n_in,
                              void* d_out, int out_size, void* d_ws, size_t ws_size,
                              hipStream_t stream) {
    const float* T_static = (const float*)d_in[0];
    const int*   U_static = (const int*)d_in[1];
    const int*   mask     = (const int*)d_in[2];
    const float* e0 = (const float*)d_in[3];
    const float* e1 = (const float*)d_in[4];
    const float* e2 = (const float*)d_in[5];
    const float* e3 = (const float*)d_in[6];
    const float* e4 = (const float*)d_in[7];
    const float* e5 = (const float*)d_in[8];
    float* out = (float*)d_out;

    unsigned short* BS = (unsigned short*)d_ws;
    size_t bs_bytes = (size_t)KSTEPS * 3 * 64 * 8 * sizeof(unsigned short); // 4.8 MB
    float* partial = (float*)((char*)d_ws + bs_bytes);  // 2000*63*48*4 = 24.2 MB

    build_uembT<<<dim3((UNP + 255) / 256, NCOL), dim3(256), 0, stream>>>(
        U_static, e0, e1, e2, e3, e4, e5, BS);
    masked_gemm<<<dim3(16, KCHUNKS), dim3(256), 0, stream>>>(mask, BS, partial);
    finalize<<<dim3(TN), dim3(64), 0, stream>>>(T_static, partial, out);
}

// Round 9
// 562.023 us; speedup vs baseline: 1.0140x; 1.0140x over previous
//
#include <hip/hip_runtime.h>
#include <hip/hip_bf16.h>

// Problem constants
#define TN 2000
#define UN 50000
#define TF 16
#define NCOL 48      // padded N: 36 emb cols + ones col (36) + 11 zero cols
#define UNP 50016    // padded K: 1563 steps * 32
#define KSTEPS 1563  // ceil(50000/32); step 1562 is the partial tail
#define KFULL 1562   // steps with all 32 k valid (50000 = 1562*32 + 16)
#define KCHUNKS 48   // best measured (R7 567.6 us; 63 was neutral-worse R8)
#define SPC 33       // ceil(1563/48)
#define MTILES 125   // 2000/16

typedef __attribute__((ext_vector_type(8))) short short8;
typedef __attribute__((ext_vector_type(4))) float f32x4;
typedef __attribute__((ext_vector_type(4))) int i32x4;

__device__ inline unsigned short f2bf(float f) {
    unsigned int x = __float_as_uint(f);
    x += 0x7FFFu + ((x >> 16) & 1u);      // round-to-nearest-even
    return (unsigned short)(x >> 16);
}

// Kernel 1: gather per-user embeddings into bf16 in MFMA B-FRAGMENT ORDER:
//   BS[((ks*3 + tile)*64 + lane)*8 + j] = B[k=ks*32+(lane>>4)*8+j][n=tile*16+(lane&15)]
// LDS-staged: block = 256 users = 8 ks-groups; phase 1 gathers into
// lds[c][u_local] (row padded 256->264 so phase-1 stores are 2-way/free and
// phase-2 b128 reads spread banks), phase 2 emits coalesced 16B/lane stores.
__global__ __launch_bounds__(256) void build_uembT(
        const int* __restrict__ U,
        const float* __restrict__ e0, const float* __restrict__ e1,
        const float* __restrict__ e2, const float* __restrict__ e3,
        const float* __restrict__ e4, const float* __restrict__ e5,
        unsigned short* __restrict__ BS) {
    __shared__ unsigned short lds[NCOL][264];
    int t = threadIdx.x;
    int u = blockIdx.x * 256 + t;
    const float* tabs[6] = {e0, e1, e2, e3, e4, e5};
    if (u < UN) {
        #pragma unroll
        for (int f = 0; f < 6; ++f) {
            int idx = U[u * 6 + f];
            #pragma unroll
            for (int h = 0; h < 6; ++h)
                lds[f * 6 + h][t] = f2bf(tabs[f][idx * 6 + h]);
        }
        lds[36][t] = 0x3F80;               // ones column -> counts
    } else {
        #pragma unroll
        for (int c = 0; c < 37; ++c) lds[c][t] = 0;
    }
    #pragma unroll
    for (int c = 37; c < NCOL; ++c) lds[c][t] = 0;
    __syncthreads();

    // phase 2: 6 chunks of 16B per thread, consecutive cid -> consecutive 16B
    size_t region = (size_t)blockIdx.x * 8 * 1536;   // ushorts; 8 ks * 3*64*8
    #pragma unroll
    for (int i = 0; i < 6; ++i) {
        int cid  = i * 256 + t;            // 0..1535
        int ksl  = cid / 192;              // local ks 0..7
        int rem  = cid - ksl * 192;
        int tile = rem >> 6;
        int l    = rem & 63;
        int g    = l >> 4, n15 = l & 15;
        int c    = tile * 16 + n15;
        int ul   = ksl * 32 + g * 8;
        int ks   = blockIdx.x * 8 + ksl;
        if (ks < KSTEPS) {
            short8 v = *(const short8*)&lds[c][ul];
            *(short8*)(BS + region + (size_t)cid * 8) = v;
        }
    }
}

// mask values are exactly 0/1, so bf16 packed pair = lo*0x3F80 + hi*0x3F800000
__device__ inline short8 mask_to_bf16(i32x4 v0, i32x4 v1) {
    union { short8 s; unsigned int i[4]; } a;
    a.i[0] = (unsigned)v0.x * 0x3F80u + (unsigned)v0.y * 0x3F800000u;
    a.i[1] = (unsigned)v0.z * 0x3F80u + (unsigned)v0.w * 0x3F800000u;
    a.i[2] = (unsigned)v1.x * 0x3F80u + (unsigned)v1.y * 0x3F800000u;
    a.i[3] = (unsigned)v1.z * 0x3F80u + (unsigned)v1.w * 0x3F800000u;
    return a.s;
}

// Kernel 2: bf16 MFMA GEMM, 2 M-tiles per wave (B fragments reused):
//   partial[m][ky][n] = sum_{k in chunk ky} mask(m,k) * Uemb[k][n]
// grid (16,KCHUNKS): slot s = blockIdx.x*4+wave handles mtile s and s+64.
__global__ __launch_bounds__(256) void masked_gemm(
        const int* __restrict__ mask, const unsigned short* __restrict__ BS,
        float* __restrict__ partial) {
    int wave = threadIdx.x >> 6;
    int lane = threadIdx.x & 63;
    int slot = blockIdx.x * 4 + wave;     // 0..63
    int mt0 = slot;                        // always < 125
    int mt1 = slot + 64;
    bool two = (mt1 < MTILES);
    int r  = lane & 15;
    int g8 = (lane >> 4) * 8;
    int ky = blockIdx.y;

    int ks0 = ky * SPC;
    int ks1 = ks0 + SPC; if (ks1 > KSTEPS) ks1 = KSTEPS;
    int ksf = (ks1 < KFULL) ? ks1 : KFULL;   // full (unguarded) steps

    f32x4 acc00 = {0,0,0,0}, acc01 = {0,0,0,0}, acc02 = {0,0,0,0};
    f32x4 acc10 = {0,0,0,0}, acc11 = {0,0,0,0}, acc12 = {0,0,0,0};

    const int* arow0 = mask + (size_t)(mt0 * 16 + r) * UN + g8;
    const int* arow1 = arow0 + (size_t)64 * 16 * UN;   // mt1 = mt0+64
    const short8* bs = (const short8*)BS + lane;       // fragment-order B

    if (two) {
        #pragma unroll 3
        for (int ks = ks0; ks < ksf; ++ks) {
            int gk = ks * 32;
            const i32x4* p0 = (const i32x4*)(arow0 + gk);
            const i32x4* p1 = (const i32x4*)(arow1 + gk);
            i32x4 u0 = p0[0], u1 = p0[1];
            i32x4 w0 = p1[0], w1 = p1[1];
            short8 a0 = mask_to_bf16(u0, u1);
            short8 a1 = mask_to_bf16(w0, w1);
            short8 f0 = bs[(size_t)(ks * 3    ) * 64];
            short8 f1 = bs[(size_t)(ks * 3 + 1) * 64];
            short8 f2 = bs[(size_t)(ks * 3 + 2) * 64];
            acc00 = __builtin_amdgcn_mfma_f32_16x16x32_bf16(a0, f0, acc00, 0, 0, 0);
            acc01 = __builtin_amdgcn_mfma_f32_16x16x32_bf16(a0, f1, acc01, 0, 0, 0);
            acc02 = __builtin_amdgcn_mfma_f32_16x16x32_bf16(a0, f2, acc02, 0, 0, 0);
            acc10 = __builtin_amdgcn_mfma_f32_16x16x32_bf16(a1, f0, acc10, 0, 0, 0);
            acc11 = __builtin_amdgcn_mfma_f32_16x16x32_bf16(a1, f1, acc11, 0, 0, 0);
            acc12 = __builtin_amdgcn_mfma_f32_16x16x32_bf16(a1, f2, acc12, 0, 0, 0);
        }
    } else {
        #pragma unroll 3
        for (int ks = ks0; ks < ksf; ++ks) {
            int gk = ks * 32;
            const i32x4* p0 = (const i32x4*)(arow0 + gk);
            i32x4 u0 = p0[0], u1 = p0[1];
            short8 a0 = mask_to_bf16(u0, u1);
            short8 f0 = bs[(size_t)(ks * 3    ) * 64];
            short8 f1 = bs[(size_t)(ks * 3 + 1) * 64];
            short8 f2 = bs[(size_t)(ks * 3 + 2) * 64];
            acc00 = __builtin_amdgcn_mfma_f32_16x16x32_bf16(a0, f0, acc00, 0, 0, 0);
            acc01 = __builtin_amdgcn_mfma_f32_16x16x32_bf16(a0, f1, acc01, 0, 0, 0);
            acc02 = __builtin_amdgcn_mfma_f32_16x16x32_bf16(a0, f2, acc02, 0, 0, 0);
        }
    }
    if (ks0 <= KFULL && ks1 > KFULL) {    // tail step (only chunk 47): k 49984..50015
        int tk = KFULL * 32;
        short8 a0 = {0,0,0,0,0,0,0,0}, a1 = {0,0,0,0,0,0,0,0};
        if (g8 < 16) {                    // k-groups at 49984, 49992 are fully valid
            const i32x4* p0 = (const i32x4*)(arow0 + tk);
            a0 = mask_to_bf16(p0[0], p0[1]);
            if (two) {
                const i32x4* p1 = (const i32x4*)(arow1 + tk);
                a1 = mask_to_bf16(p1[0], p1[1]);
            }
        }
        short8 t0 = bs[(size_t)(KFULL * 3    ) * 64];
        short8 t1 = bs[(size_t)(KFULL * 3 + 1) * 64];
        short8 t2 = bs[(size_t)(KFULL * 3 + 2) * 64];
        acc00 = __builtin_amdgcn_mfma_f32_16x16x32_bf16(a0, t0, acc00, 0, 0, 0);
        acc01 = __builtin_amdgcn_mfma_f32_16x16x32_bf16(a0, t1, acc01, 0, 0, 0);
        acc02 = __builtin_amdgcn_mfma_f32_16x16x32_bf16(a0, t2, acc02, 0, 0, 0);
        if (two) {
            acc10 = __builtin_amdgcn_mfma_f32_16x16x32_bf16(a1, t0, acc10, 0, 0, 0);
            acc11 = __builtin_amdgcn_mfma_f32_16x16x32_bf16(a1, t1, acc11, 0, 0, 0);
            acc12 = __builtin_amdgcn_mfma_f32_16x16x32_bf16(a1, t2, acc12, 0, 0, 0);
        }
    }

    // C/D layout: col = lane&15, row = (lane>>4)*4 + reg   [HW-verified]
    int rbase = (lane >> 4) * 4;
    int col   = lane & 15;
    #pragma unroll
    for (int reg = 0; reg < 4; ++reg) {
        size_t rb = ((size_t)(mt0 * 16 + rbase + reg) * KCHUNKS + ky) * NCOL;
        partial[rb + col]      = acc00[reg];
        partial[rb + col + 16] = acc01[reg];
        if (col < 5) partial[rb + col + 32] = acc02[reg];
    }
    if (two) {
        #pragma unroll
        for (int reg = 0; reg < 4; ++reg) {
            size_t rb = ((size_t)(mt1 * 16 + rbase + reg) * KCHUNKS + ky) * NCOL;
            partial[rb + col]      = acc10[reg];
            partial[rb + col + 16] = acc11[reg];
            if (col < 5) partial[rb + col + 32] = acc12[reg];
        }
    }
}

// Kernel 3: out[t] = concat(T_static[t], sum_ky partial[t][ky][0:36] / sum_ky partial[t][ky][36])
__global__ void finalize(const float* __restrict__ T_static,
                         const float* __restrict__ partial,
                         float* __restrict__ out) {
    int t = blockIdx.x;
    int c = threadIdx.x;
    if (c >= TF + 36) return;
    float v;
    if (c < TF) {
        v = T_static[(size_t)t * TF + c];
    } else {
        int n = c - TF;
        const float* base = partial + (size_t)t * KCHUNKS * NCOL;
        float s = 0.f, cnt = 0.f;
        #pragma unroll 6
        for (int ky = 0; ky < KCHUNKS; ++ky) {
            s   += base[ky * NCOL + n];
            cnt += base[ky * NCOL + 36];
        }
        v = s / cnt;
    }
    out[(size_t)t * (TF + 36) + c] = v;
}

extern "C" void kernel_launch(void* const* d_in, const int* in_sizes, int n_in,
                              void* d_out, int out_size, void* d_ws, size_t ws_size,
                              hipStream_t stream) {
    const float* T_static = (const float*)d_in[0];
    const int*   U_static = (const int*)d_in[1];
    const int*   mask     = (const int*)d_in[2];
    const float* e0 = (const float*)d_in[3];
    const float* e1 = (const float*)d_in[4];
    const float* e2 = (const float*)d_in[5];
    const float* e3 = (const float*)d_in[6];
    const float* e4 = (const float*)d_in[7];
    const float* e5 = (const float*)d_in[8];
    float* out = (float*)d_out;

    unsigned short* BS = (unsigned short*)d_ws;
    size_t bs_bytes = (size_t)KSTEPS * 3 * 64 * 8 * sizeof(unsigned short); // 4.8 MB
    float* partial = (float*)((char*)d_ws + bs_bytes);  // 2000*48*48*4 = 18.4 MB

    // 196 blocks: each handles 256 users = 8 ks-groups (guarded at KSTEPS)
    build_uembT<<<dim3((UNP + 255) / 256), dim3(256), 0, stream>>>(
        U_static, e0, e1, e2, e3, e4, e5, BS);
    masked_gemm<<<dim3(16, KCHUNKS), dim3(256), 0, stream>>>(mask, BS, partial);
    finalize<<<dim3(TN), dim3(64), 0, stream>>>(T_static, partial, out);
}